// Round 3
// baseline (1453.311 us; speedup 1.0000x reference)
//
#include <hip/hip_runtime.h>
#include <stdint.h>

#define N_NODES 100000
#define MT      782          // 128-row tiles (k3)
#define MT64    1564         // 64-row tiles (k1,k2)
#define MPAD    (MT*128)     // 100096
#define IN_DIM  2048
#define HID     512
#define OUTD    128
#define NG      512
#define LOG2F_  0.69314718055994531f

typedef __attribute__((ext_vector_type(4))) float f32x4;
typedef __attribute__((ext_vector_type(8))) short bf16x8;
typedef __attribute__((ext_vector_type(4))) short bf16x4;

typedef const __attribute__((address_space(1))) unsigned int gas_u32;
typedef __attribute__((address_space(3))) unsigned int las_u32;

__device__ __forceinline__ void gload_lds16(const void* g, void* lds) {
  __builtin_amdgcn_global_load_lds((gas_u32*)g, (las_u32*)lds, 16, 0, 0);
}

__device__ __forceinline__ short f2bf(float f) {
  unsigned u = __builtin_bit_cast(unsigned, f);
  u = (u + 0x7fffu + ((u >> 16) & 1u)) >> 16;
  return (short)u;
}
__device__ __forceinline__ float bf2f(short s) {
  unsigned u = ((unsigned)(unsigned short)s) << 16;
  return __builtin_bit_cast(float, u);
}

__device__ __forceinline__ f32x4 mfma16(bf16x8 a, bf16x8 b, f32x4 c) {
  return __builtin_amdgcn_mfma_f32_16x16x32_bf16(a, b, c, 0, 0, 0);
}

// ---------------- prep: transpose+cast weights to bf16 B^T layouts ------------
__global__ void kprep(const float* __restrict__ W1, const float* __restrict__ Wj,
                      const float* __restrict__ W2, const float* __restrict__ W3,
                      const float* __restrict__ ge,
                      short* __restrict__ wcat, short* __restrict__ w2t,
                      short* __restrict__ w3t, short* __restrict__ gencb) {
  const int S1 = 640 * 2048, S2 = 512 * 512, S3 = 128 * 512, S4 = 512 * 128;
  int t = blockIdx.x * 256 + threadIdx.x;
  if (t < S1) {
    int n = t >> 11, k = t & 2047;
    float v = (n < 512) ? W1[(size_t)k * 512 + n] : Wj[(size_t)k * 128 + (n - 512)];
    wcat[t] = f2bf(v);
  } else {
    t -= S1;
    if (t < S2) {
      int n = t >> 9, k = t & 511;
      w2t[t] = f2bf(W2[(size_t)k * 512 + n]);
    } else {
      t -= S2;
      if (t < S3) {
        int n = t >> 9, k = t & 511;
        w3t[t] = f2bf(W3[(size_t)k * 128 + n]);
      } else {
        t -= S3;
        if (t < S4) gencb[t] = f2bf(ge[t]);
      }
    }
  }
}

// ---- K1: feat(f32)[64 rows] @ [W1|Wj]^T(640) -> h1 (relu+b1), jump (+b3+bj) --
// Full N per block (feat read once). LDS double-buffered, k-slot-major layout
// [slot=k/8][row][8bf16]: unit u = slot*ROWS+row at byte offset u*16.
__global__ __launch_bounds__(512, 2) void k1(
    const float* __restrict__ feat, const short* __restrict__ wcat,
    const float* __restrict__ b1, const float* __restrict__ b3,
    const float* __restrict__ bj,
    short* __restrict__ h1, short* __restrict__ jmp) {
  __shared__ __align__(16) short As[2][4 * 64 * 8];    // 4 KB each
  __shared__ __align__(16) short Bs[2][4 * 640 * 8];   // 40 KB each
  const int tid = threadIdx.x;
  const int lane = tid & 63, w = tid >> 6;             // 8 waves, 1M x 8N
  const int l16 = lane & 15, lh = lane >> 4;
  const int m0 = blockIdx.x * 64;

  f32x4 acc[4][5];
#pragma unroll
  for (int m = 0; m < 4; m++)
#pragma unroll
    for (int n = 0; n < 5; n++) acc[m][n] = (f32x4){0.f, 0.f, 0.f, 0.f};

  // A staging: thread t handles row=t>>3, f32 cols (t&7)*4..+3 of the k-tile
  const int arow = tid >> 3;
  const bool aok = (m0 + arow) < N_NODES;
  const float* ap = feat + (size_t)(m0 + arow) * IN_DIM + (tid & 7) * 4;
  const int aoff = (((tid & 7) >> 1) * 64 + arow) * 8 + (tid & 1) * 4;  // shorts

  // B staging: 5 gload_lds per thread; unit u = s*512+tid -> (slot=u/640,row=u%640)
  const short* bsrc[5];
  int bdst[5];
#pragma unroll
  for (int s = 0; s < 5; s++) {
    int u = s * 512 + tid;
    int slot = u / 640;
    int row = u - slot * 640;
    bsrc[s] = wcat + (size_t)row * IN_DIM + slot * 8;
    bdst[s] = u * 8;  // shorts
  }

  // prologue: stage kt=0 into buffer 0
  {
    f32x4 a0 = aok ? *(const f32x4*)ap : (f32x4){0.f, 0.f, 0.f, 0.f};
    bf16x4 av;
#pragma unroll
    for (int q = 0; q < 4; q++) av[q] = f2bf(a0[q]);
    *(bf16x4*)(&As[0][aoff]) = av;
#pragma unroll
    for (int s = 0; s < 5; s++) gload_lds16(bsrc[s], &Bs[0][bdst[s]]);
  }
  __syncthreads();

  for (int kt = 0; kt < IN_DIM / 32; ++kt) {
    const int cur = kt & 1, nxt = cur ^ 1;
    f32x4 an = (f32x4){0.f, 0.f, 0.f, 0.f};
    if (kt < IN_DIM / 32 - 1) {
      if (aok) an = *(const f32x4*)(ap + (kt + 1) * 32);
#pragma unroll
      for (int s = 0; s < 5; s++)
        gload_lds16(bsrc[s] + (kt + 1) * 32, &Bs[nxt][bdst[s]]);
    }
    bf16x8 a[4], b[5];
#pragma unroll
    for (int m = 0; m < 4; m++)
      a[m] = *(const bf16x8*)(&As[cur][(lh * 64 + m * 16 + l16) * 8]);
#pragma unroll
    for (int n = 0; n < 5; n++)
      b[n] = *(const bf16x8*)(&Bs[cur][(lh * 640 + w * 80 + n * 16 + l16) * 8]);
#pragma unroll
    for (int m = 0; m < 4; m++)
#pragma unroll
      for (int n = 0; n < 5; n++) acc[m][n] = mfma16(a[m], b[n], acc[m][n]);
    if (kt < IN_DIM / 32 - 1) {
      bf16x4 av;
#pragma unroll
      for (int q = 0; q < 4; q++) av[q] = f2bf(an[q]);
      *(bf16x4*)(&As[nxt][aoff]) = av;
    }
    __syncthreads();
  }

#pragma unroll
  for (int n = 0; n < 5; n++) {
    const int c = w * 80 + n * 16 + l16;   // fragment entirely on one side of 512
    if (c < 512) {
      const float bias = b1[c];
#pragma unroll
      for (int m = 0; m < 4; m++) {
        const int row = m0 + m * 16 + lh * 4;
#pragma unroll
        for (int r = 0; r < 4; r++) {
          float v = acc[m][n][r] + bias;
          v = v > 0.f ? v : 0.f;
          h1[(size_t)(row + r) * HID + c] = f2bf(v);
        }
      }
    } else {
      const int cj = c - 512;
      const float bias = b3[cj] + bj[cj];
#pragma unroll
      for (int m = 0; m < 4; m++) {
        const int row = m0 + m * 16 + lh * 4;
#pragma unroll
        for (int r = 0; r < 4; r++)
          jmp[(size_t)(row + r) * OUTD + cj] = f2bf(acc[m][n][r] + bias);
      }
    }
  }
}

// ---------------- K2: h1[64 rows] @ W2^T (full N=512) -> h2 (relu+b2) ---------
__global__ __launch_bounds__(512, 4) void k2(
    const short* __restrict__ h1, const short* __restrict__ w2t,
    const float* __restrict__ b2, short* __restrict__ h2) {
  __shared__ __align__(16) short As[2][4 * 64 * 8];    // 4 KB each
  __shared__ __align__(16) short Bs[2][4 * 512 * 8];   // 32 KB each
  const int tid = threadIdx.x;
  const int lane = tid & 63, w = tid >> 6;             // 8 waves, 1M x 8N
  const int l16 = lane & 15, lh = lane >> 4;
  const int m0 = blockIdx.x * 64;

  f32x4 acc[4][4];
#pragma unroll
  for (int m = 0; m < 4; m++)
#pragma unroll
    for (int n = 0; n < 4; n++) acc[m][n] = (f32x4){0.f, 0.f, 0.f, 0.f};

  // A: 256 units (4 slots x 64 rows), threads < 256 (waves 0-3)
  const short* asrc = h1 + (size_t)(m0 + (tid & 63)) * HID + (tid >> 6) * 8;
  const int adst = tid * 8;  // shorts
  // B: 2048 units, 4 issues
  const short* bsrc[4];
  int bdst[4];
#pragma unroll
  for (int s = 0; s < 4; s++) {
    int u = s * 512 + tid;
    bsrc[s] = w2t + (size_t)(u & 511) * HID + (u >> 9) * 8;
    bdst[s] = u * 8;
  }

  {
    if (tid < 256) gload_lds16(asrc, &As[0][adst]);
#pragma unroll
    for (int s = 0; s < 4; s++) gload_lds16(bsrc[s], &Bs[0][bdst[s]]);
  }
  __syncthreads();

  for (int kt = 0; kt < HID / 32; ++kt) {
    const int cur = kt & 1, nxt = cur ^ 1;
    if (kt < HID / 32 - 1) {
      if (tid < 256) gload_lds16(asrc + (kt + 1) * 32, &As[nxt][adst]);
#pragma unroll
      for (int s = 0; s < 4; s++)
        gload_lds16(bsrc[s] + (kt + 1) * 32, &Bs[nxt][bdst[s]]);
    }
    bf16x8 a[4], b[4];
#pragma unroll
    for (int m = 0; m < 4; m++)
      a[m] = *(const bf16x8*)(&As[cur][(lh * 64 + m * 16 + l16) * 8]);
#pragma unroll
    for (int n = 0; n < 4; n++)
      b[n] = *(const bf16x8*)(&Bs[cur][(lh * 512 + w * 64 + n * 16 + l16) * 8]);
#pragma unroll
    for (int m = 0; m < 4; m++)
#pragma unroll
      for (int n = 0; n < 4; n++) acc[m][n] = mfma16(a[m], b[n], acc[m][n]);
    __syncthreads();
  }

#pragma unroll
  for (int n = 0; n < 4; n++) {
    const int c = w * 64 + n * 16 + l16;
    const float bias = b2[c];
#pragma unroll
    for (int m = 0; m < 4; m++) {
      const int row = m0 + m * 16 + lh * 4;
#pragma unroll
      for (int r = 0; r < 4; r++) {
        float v = acc[m][n][r] + bias;
        v = v > 0.f ? v : 0.f;
        h2[(size_t)(row + r) * HID + c] = f2bf(v);
      }
    }
  }
}

// ---------------- K3: l_enc = h2@W3^T + jump; res = l_enc@g_enc^T; JS loss ----
__global__ __launch_bounds__(256, 2) void k3(
    const short* __restrict__ h2, const short* __restrict__ w3t,
    const short* __restrict__ jmp, const short* __restrict__ genc,
    const int* __restrict__ gid, float* __restrict__ partials) {
  __shared__ __align__(16) short As[2][4 * 128 * 8];   // 8 KB each
  __shared__ __align__(16) short Bs[2][4 * 128 * 8];   // 8 KB each
  __shared__ __align__(16) short Ll[128 * 128];        // l_enc, XOR-swizzled rows
  __shared__ int gids[128];
  __shared__ float sred[8];
  const int mt = blockIdx.x;
  const int m0 = mt * 128;
  const int tid = threadIdx.x;
  const int lane = tid & 63, wid = tid >> 6;
  const int wr = wid >> 1, wc = wid & 1;
  const int l16 = lane & 15, lh = lane >> 4;

  if (tid < 128) {
    int r = m0 + tid;
    gids[tid] = (r < N_NODES) ? gid[r] : -1;
  }

  f32x4 acc[4][4];
#pragma unroll
  for (int i = 0; i < 4; i++)
#pragma unroll
    for (int j = 0; j < 4; j++) acc[i][j] = (f32x4){0.f, 0.f, 0.f, 0.f};

  // A/B: 512 units each (4 slots x 128 rows), 2 issues x 256 threads
  const short* asrc[2];
  const short* bsrc[2];
  int sdst[2];
#pragma unroll
  for (int s = 0; s < 2; s++) {
    int u = s * 256 + tid;
    asrc[s] = h2 + (size_t)(m0 + (u & 127)) * HID + (u >> 7) * 8;
    bsrc[s] = w3t + (size_t)(u & 127) * HID + (u >> 7) * 8;
    sdst[s] = u * 8;
  }

  {
#pragma unroll
    for (int s = 0; s < 2; s++) {
      gload_lds16(asrc[s], &As[0][sdst[s]]);
      gload_lds16(bsrc[s], &Bs[0][sdst[s]]);
    }
  }
  __syncthreads();

  for (int kt = 0; kt < HID / 32; ++kt) {
    const int cur = kt & 1, nxt = cur ^ 1;
    if (kt < HID / 32 - 1) {
#pragma unroll
      for (int s = 0; s < 2; s++) {
        gload_lds16(asrc[s] + (kt + 1) * 32, &As[nxt][sdst[s]]);
        gload_lds16(bsrc[s] + (kt + 1) * 32, &Bs[nxt][sdst[s]]);
      }
    }
    bf16x8 a[4], b[4];
#pragma unroll
    for (int i = 0; i < 4; i++)
      a[i] = *(const bf16x8*)(&As[cur][(lh * 128 + wr * 64 + i * 16 + l16) * 8]);
#pragma unroll
    for (int j = 0; j < 4; j++)
      b[j] = *(const bf16x8*)(&Bs[cur][(lh * 128 + wc * 64 + j * 16 + l16) * 8]);
#pragma unroll
    for (int i = 0; i < 4; i++)
#pragma unroll
      for (int j = 0; j < 4; j++) acc[i][j] = mfma16(a[i], b[j], acc[i][j]);
    __syncthreads();
  }

  // epilogue: l_enc = acc + jump (jump already holds b3+bj) -> Ll (swizzled bf16)
#pragma unroll
  for (int j = 0; j < 4; j++) {
    const int col = wc * 64 + j * 16 + l16;
#pragma unroll
    for (int i = 0; i < 4; i++) {
      const int rowb = wr * 64 + i * 16 + lh * 4;
#pragma unroll
      for (int r = 0; r < 4; r++) {
        const int row = rowb + r;
        float v = acc[i][j][r] + bf2f(jmp[(size_t)(m0 + row) * OUTD + col]);
        unsigned byte = (unsigned)row * 256u +
                        (((unsigned)col * 2u) ^ (((unsigned)(row & 7)) << 4));
        *(short*)((char*)Ll + byte) = f2bf(v);
      }
    }
  }
  __syncthreads();

  int myg[4][4];
#pragma unroll
  for (int i = 0; i < 4; i++)
#pragma unroll
    for (int r = 0; r < 4; r++) myg[i][r] = gids[wr * 64 + i * 16 + lh * 4 + r];

  float pacc = 0.f, nacc = 0.f;
  for (int nc = 0; nc < 4; ++nc) {
    f32x4 a2[4][4];
#pragma unroll
    for (int i = 0; i < 4; i++)
#pragma unroll
      for (int j = 0; j < 4; j++) a2[i][j] = (f32x4){0.f, 0.f, 0.f, 0.f};
#pragma unroll
    for (int ks = 0; ks < 4; ++ks) {
      bf16x8 af[4], bg[4];
#pragma unroll
      for (int i = 0; i < 4; i++) {
        const int row = wr * 64 + i * 16 + l16;
        unsigned byte = (unsigned)row * 256u +
                        (((unsigned)(ks * 64 + lh * 16)) ^ (((unsigned)(row & 7)) << 4));
        af[i] = *(const bf16x8*)((const char*)Ll + byte);
      }
#pragma unroll
      for (int j = 0; j < 4; j++) {
        const int g = nc * 128 + wc * 64 + j * 16 + l16;
        bg[j] = *(const bf16x8*)(genc + (size_t)g * OUTD + ks * 32 + lh * 8);
      }
#pragma unroll
      for (int i = 0; i < 4; i++)
#pragma unroll
        for (int j = 0; j < 4; j++) a2[i][j] = mfma16(af[i], bg[j], a2[i][j]);
    }
#pragma unroll
    for (int j = 0; j < 4; j++) {
      const int g = nc * 128 + wc * 64 + j * 16 + l16;
#pragma unroll
      for (int i = 0; i < 4; i++) {
#pragma unroll
        for (int r = 0; r < 4; r++) {
          float rv = a2[i][j][r];
          int gr = myg[i][r];
          float t = __expf(-fabsf(rv));
          float lg = __logf(1.f + t);
          if (gr == g)
            pacc += LOG2F_ - (fmaxf(-rv, 0.f) + lg);
          else if (gr >= 0)
            nacc += (fmaxf(rv, 0.f) + lg) - LOG2F_;
        }
      }
    }
  }

#pragma unroll
  for (int o = 32; o; o >>= 1) {
    pacc += __shfl_down(pacc, o);
    nacc += __shfl_down(nacc, o);
  }
  if (lane == 0) { sred[wid] = pacc; sred[4 + wid] = nacc; }
  __syncthreads();
  if (tid == 0) {
    partials[2 * mt] = sred[0] + sred[1] + sred[2] + sred[3];
    partials[2 * mt + 1] = sred[4] + sred[5] + sred[6] + sred[7];
  }
}

// ---------------- K4: deterministic final reduction ---------------------------
__global__ void k4(const float* __restrict__ partials, float* __restrict__ out) {
  const int tid = threadIdx.x;
  float p = 0.f, n = 0.f;
  for (int i = tid; i < MT; i += 256) {
    p += partials[2 * i];
    n += partials[2 * i + 1];
  }
#pragma unroll
  for (int o = 32; o; o >>= 1) {
    p += __shfl_down(p, o);
    n += __shfl_down(n, o);
  }
  __shared__ float sp[4], sn[4];
  const int wid = tid >> 6, lane = tid & 63;
  if (lane == 0) { sp[wid] = p; sn[wid] = n; }
  __syncthreads();
  if (tid == 0) {
    float P = sp[0] + sp[1] + sp[2] + sp[3];
    float Nn = sn[0] + sn[1] + sn[2] + sn[3];
    out[0] = Nn / (100000.0f * 511.0f) - P / 100000.0f;
  }
}

extern "C" void kernel_launch(void* const* d_in, const int* in_sizes, int n_in,
                              void* d_out, int out_size, void* d_ws, size_t ws_size,
                              hipStream_t stream) {
  const float* feat = (const float*)d_in[0];
  const float* genc_f = (const float*)d_in[1];
  const int* gid = (const int*)d_in[2];
  const float* W1 = (const float*)d_in[3];
  const float* b1 = (const float*)d_in[4];
  const float* W2 = (const float*)d_in[5];
  const float* b2 = (const float*)d_in[6];
  const float* W3 = (const float*)d_in[7];
  const float* b3 = (const float*)d_in[8];
  const float* Wj = (const float*)d_in[9];
  const float* bj = (const float*)d_in[10];
  float* out = (float*)d_out;

  char* ws = (char*)d_ws;
  float* partials = (float*)ws;                       // 782*2 f32
  short* wcat = (short*)(ws + 8192);                  // [640][2048] bf16
  short* w2t = wcat + (size_t)640 * 2048;             // [512][512]
  short* w3t = w2t + (size_t)512 * 512;               // [128][512]
  short* gencb = w3t + (size_t)128 * 512;             // [512][128]
  short* h1 = gencb + (size_t)512 * 128;              // [MPAD][512]
  short* h2 = h1 + (size_t)MPAD * 512;                // [MPAD][512]
  short* jmp = h2 + (size_t)MPAD * 512;               // [MPAD][128]

  kprep<<<6656, 256, 0, stream>>>(W1, Wj, W2, W3, genc_f, wcat, w2t, w3t, gencb);
  k1<<<MT64, 512, 0, stream>>>(feat, wcat, b1, b3, bj, h1, jmp);
  k2<<<MT64, 512, 0, stream>>>(h1, w2t, b2, h2);
  k3<<<MT, 256, 0, stream>>>(h2, w3t, jmp, gencb, gid, partials);
  k4<<<1, 256, 0, stream>>>(partials, out);
}

// Round 4
// 766.625 us; speedup vs baseline: 1.8957x; 1.8957x over previous
//
#include <hip/hip_runtime.h>
#include <stdint.h>

#define N_NODES 100000
#define MT      782          // 128-row tiles (k3)
#define MT64    1564         // 64-row tiles (k1,k2)
#define MPAD    (MT*128)     // 100096
#define IN_DIM  2048
#define HID     512
#define OUTD    128
#define NG      512
#define LOG2F_  0.69314718055994531f

typedef __attribute__((ext_vector_type(4))) float f32x4;
typedef __attribute__((ext_vector_type(8))) short bf16x8;
typedef __attribute__((ext_vector_type(4))) short bf16x4;

typedef const __attribute__((address_space(1))) unsigned int gas_u32;
typedef __attribute__((address_space(3))) unsigned int las_u32;

__device__ __forceinline__ void gload_lds16(const void* g, void* lds) {
  __builtin_amdgcn_global_load_lds((gas_u32*)g, (las_u32*)lds, 16, 0, 0);
}

__device__ __forceinline__ short f2bf(float f) {
  unsigned u = __builtin_bit_cast(unsigned, f);
  u = (u + 0x7fffu + ((u >> 16) & 1u)) >> 16;
  return (short)u;
}
__device__ __forceinline__ float bf2f(short s) {
  unsigned u = ((unsigned)(unsigned short)s) << 16;
  return __builtin_bit_cast(float, u);
}

__device__ __forceinline__ f32x4 mfma16(bf16x8 a, bf16x8 b, f32x4 c) {
  return __builtin_amdgcn_mfma_f32_16x16x32_bf16(a, b, c, 0, 0, 0);
}

// ---------------- prep: weights -> bf16, frag-major for k1/k2 B operands ------
// wcatF: frag-major [ng=n/16][kt=k/32][lh=(k/8)%4][l16=n%16][e=k%8]
//        => a wave's b-frag (ng,kt) is one contiguous 1KB block, lane*8 shorts.
// w2tF : same, K=512 -> kt in [0,16).
// w3t  : row-major [n][k] (k3 uses gload_lds).  gencb: row-major [g][k].
__global__ void kprep(const float* __restrict__ W1, const float* __restrict__ Wj,
                      const float* __restrict__ W2, const float* __restrict__ W3,
                      const float* __restrict__ ge,
                      short* __restrict__ wcatF, short* __restrict__ w2tF,
                      short* __restrict__ w3t, short* __restrict__ gencb) {
  const int S1 = 640 * 2048, S2 = 512 * 512, S3 = 128 * 512, S4 = 512 * 128;
  int t = blockIdx.x * 256 + threadIdx.x;
  if (t < S1) {
    int k = t / 640, n = t - k * 640;          // consecutive t -> consecutive n
    float v = (n < 512) ? W1[(size_t)k * 512 + n] : Wj[(size_t)k * 128 + (n - 512)];
    int idx = ((((n >> 4) * 64 + (k >> 5)) * 4 + ((k >> 3) & 3)) * 16 + (n & 15)) * 8 + (k & 7);
    wcatF[idx] = f2bf(v);
  } else {
    t -= S1;
    if (t < S2) {
      int k = t >> 9, n = t & 511;
      int idx = ((((n >> 4) * 16 + (k >> 5)) * 4 + ((k >> 3) & 3)) * 16 + (n & 15)) * 8 + (k & 7);
      w2tF[idx] = f2bf(W2[(size_t)k * 512 + n]);
    } else {
      t -= S2;
      if (t < S3) {
        int n = t >> 9, k = t & 511;
        w3t[t] = f2bf(W3[(size_t)k * 128 + n]);
      } else {
        t -= S3;
        if (t < S4) gencb[t] = f2bf(ge[t]);
      }
    }
  }
}

// ---- K1: feat(f32)[64 rows] @ [W1|Wj]^T(640) -> h1 (relu+b1), jump (+b3+bj) --
// A: tiny LDS (k-slot-major, double-buffered 2x4KB), raw s_barrier (no vmcnt
// drain) so 2-deep feat reg-prefetch survives. B: direct global->reg frag
// loads from frag-major wcatF (compiler-counted vmcnt pipelining, no LDS).
__global__ __launch_bounds__(512, 3) void k1(
    const float* __restrict__ feat, const short* __restrict__ wcatF,
    const float* __restrict__ b1, const float* __restrict__ b3,
    const float* __restrict__ bj,
    short* __restrict__ h1, short* __restrict__ jmp) {
  __shared__ __align__(16) short As[2][2048];  // [slot=k/8][row][e] 4KB each
  const int tid = threadIdx.x;
  const int lane = tid & 63, w = tid >> 6;     // 8 waves, 1M x 8N
  const int l16 = lane & 15, lh = lane >> 4;
  const int m0 = blockIdx.x * 64;

  f32x4 acc[4][5];
#pragma unroll
  for (int m = 0; m < 4; m++)
#pragma unroll
    for (int n = 0; n < 5; n++) acc[m][n] = (f32x4){0.f, 0.f, 0.f, 0.f};

  // A staging: thread t: row=t>>3, f32 k-chunk (t&7)*4
  const int arow = tid >> 3;
  const bool aok = (m0 + arow) < N_NODES;
  const float* ap = feat + (size_t)(m0 + arow) * IN_DIM + (tid & 7) * 4;
  const int aoff = (((tid & 7) >> 1) * 64 + arow) * 8 + (tid & 1) * 4;  // shorts

  // B frag pointers: frag (ng = w*5+n, kt) at (ng*64+kt)*512 + lane*8
  const short* bp[5];
#pragma unroll
  for (int n = 0; n < 5; n++) bp[n] = wcatF + ((size_t)(w * 5 + n) * 64) * 512 + lane * 8;

  const f32x4 zf = (f32x4){0.f, 0.f, 0.f, 0.f};
  f32x4 ar0 = aok ? *(const f32x4*)(ap + 0) : zf;        // k-tile 0
  f32x4 ar1 = aok ? *(const f32x4*)(ap + 32) : zf;       // k-tile 1
  {
    bf16x4 av;
#pragma unroll
    for (int q = 0; q < 4; q++) av[q] = f2bf(ar0[q]);
    *(bf16x4*)(&As[0][aoff]) = av;
  }
  asm volatile("s_waitcnt lgkmcnt(0)" ::: "memory");
  __builtin_amdgcn_s_barrier();

#define K1_STEP(KT, CUR, AR_W, AR_L)                                          \
  {                                                                           \
    bf16x8 b[5];                                                              \
    _Pragma("unroll")                                                         \
    for (int n = 0; n < 5; n++)                                               \
      b[n] = *(const bf16x8*)(bp[n] + (KT) * 512);                            \
    if ((KT) + 2 < 64) AR_L = aok ? *(const f32x4*)(ap + ((KT) + 2) * 32) : zf;\
    if ((KT) + 1 < 64) {                                                      \
      bf16x4 av;                                                              \
      _Pragma("unroll")                                                       \
      for (int q = 0; q < 4; q++) av[q] = f2bf(AR_W[q]);                      \
      *(bf16x4*)(&As[(CUR) ^ 1][aoff]) = av;                                  \
    }                                                                         \
    bf16x8 a[4];                                                              \
    _Pragma("unroll")                                                         \
    for (int m = 0; m < 4; m++)                                               \
      a[m] = *(const bf16x8*)(&As[CUR][(lh * 64 + m * 16 + l16) * 8]);        \
    _Pragma("unroll")                                                         \
    for (int m = 0; m < 4; m++)                                               \
      _Pragma("unroll")                                                       \
      for (int n = 0; n < 5; n++) acc[m][n] = mfma16(a[m], b[n], acc[m][n]);  \
    asm volatile("s_waitcnt lgkmcnt(0)" ::: "memory");                        \
    __builtin_amdgcn_s_barrier();                                             \
  }

  for (int kt = 0; kt < 64; kt += 2) {
    K1_STEP(kt, 0, ar1, ar0)       // writes As[1] with k-tile kt+1; loads kt+2
    K1_STEP(kt + 1, 1, ar0, ar1)   // writes As[0] with k-tile kt+2; loads kt+3
  }
#undef K1_STEP

#pragma unroll
  for (int n = 0; n < 5; n++) {
    const int c = w * 80 + n * 16 + l16;   // frag entirely on one side of 512
    if (c < 512) {
      const float bias = b1[c];
#pragma unroll
      for (int m = 0; m < 4; m++) {
        const int row = m0 + m * 16 + lh * 4;
#pragma unroll
        for (int r = 0; r < 4; r++) {
          float v = acc[m][n][r] + bias;
          v = v > 0.f ? v : 0.f;
          h1[(size_t)(row + r) * HID + c] = f2bf(v);
        }
      }
    } else {
      const int cj = c - 512;
      const float bias = b3[cj] + bj[cj];
#pragma unroll
      for (int m = 0; m < 4; m++) {
        const int row = m0 + m * 16 + lh * 4;
#pragma unroll
        for (int r = 0; r < 4; r++)
          jmp[(size_t)(row + r) * OUTD + cj] = f2bf(acc[m][n][r] + bias);
      }
    }
  }
}

// ---------------- K2: h1[64 rows] @ W2^T (full N=512) -> h2 (relu+b2) ---------
__global__ __launch_bounds__(512, 3) void k2(
    const short* __restrict__ h1, const short* __restrict__ w2tF,
    const float* __restrict__ b2, short* __restrict__ h2) {
  __shared__ __align__(16) short As[2][2048];
  const int tid = threadIdx.x;
  const int lane = tid & 63, w = tid >> 6;     // 8 waves, 1M x 8N
  const int l16 = lane & 15, lh = lane >> 4;
  const int m0 = blockIdx.x * 64;

  f32x4 acc[4][4];
#pragma unroll
  for (int m = 0; m < 4; m++)
#pragma unroll
    for (int n = 0; n < 4; n++) acc[m][n] = (f32x4){0.f, 0.f, 0.f, 0.f};

  const int arow = tid >> 3;
  const short* ap = h1 + (size_t)(m0 + arow) * HID + (tid & 7) * 4;
  const int aoff = (((tid & 7) >> 1) * 64 + arow) * 8 + (tid & 1) * 4;

  const short* bp[4];
#pragma unroll
  for (int n = 0; n < 4; n++) bp[n] = w2tF + ((size_t)(w * 4 + n) * 16) * 512 + lane * 8;

  bf16x4 ar0 = *(const bf16x4*)(ap + 0);
  bf16x4 ar1 = *(const bf16x4*)(ap + 32);
  *(bf16x4*)(&As[0][aoff]) = ar0;
  asm volatile("s_waitcnt lgkmcnt(0)" ::: "memory");
  __builtin_amdgcn_s_barrier();

#define K2_STEP(KT, CUR, AR_W, AR_L)                                          \
  {                                                                           \
    bf16x8 b[4];                                                              \
    _Pragma("unroll")                                                         \
    for (int n = 0; n < 4; n++)                                               \
      b[n] = *(const bf16x8*)(bp[n] + (KT) * 512);                            \
    if ((KT) + 2 < 16) AR_L = *(const bf16x4*)(ap + ((KT) + 2) * 32);         \
    if ((KT) + 1 < 16) *(bf16x4*)(&As[(CUR) ^ 1][aoff]) = AR_W;               \
    bf16x8 a[4];                                                              \
    _Pragma("unroll")                                                         \
    for (int m = 0; m < 4; m++)                                               \
      a[m] = *(const bf16x8*)(&As[CUR][(lh * 64 + m * 16 + l16) * 8]);        \
    _Pragma("unroll")                                                         \
    for (int m = 0; m < 4; m++)                                               \
      _Pragma("unroll")                                                       \
      for (int n = 0; n < 4; n++) acc[m][n] = mfma16(a[m], b[n], acc[m][n]);  \
    asm volatile("s_waitcnt lgkmcnt(0)" ::: "memory");                        \
    __builtin_amdgcn_s_barrier();                                             \
  }

  for (int kt = 0; kt < 16; kt += 2) {
    K2_STEP(kt, 0, ar1, ar0)
    K2_STEP(kt + 1, 1, ar0, ar1)
  }
#undef K2_STEP

#pragma unroll
  for (int n = 0; n < 4; n++) {
    const int c = w * 64 + n * 16 + l16;
    const float bias = b2[c];
#pragma unroll
    for (int m = 0; m < 4; m++) {
      const int row = m0 + m * 16 + lh * 4;
#pragma unroll
      for (int r = 0; r < 4; r++) {
        float v = acc[m][n][r] + bias;
        v = v > 0.f ? v : 0.f;
        h2[(size_t)(row + r) * HID + c] = f2bf(v);
      }
    }
  }
}

// ---------------- K3: l_enc = h2@W3^T + jump; res = l_enc@g_enc^T; JS loss ----
__global__ __launch_bounds__(256, 2) void k3(
    const short* __restrict__ h2, const short* __restrict__ w3t,
    const short* __restrict__ jmp, const short* __restrict__ genc,
    const int* __restrict__ gid, float* __restrict__ partials) {
  __shared__ __align__(16) short As[128 * 32];
  __shared__ __align__(16) short Bs[128 * 32];
  __shared__ __align__(16) short Ll[128 * 128];  // l_enc, XOR-swizzled rows
  __shared__ int gids[128];
  __shared__ float sred[8];
  const int mt = blockIdx.x;
  const int m0 = mt * 128;
  const int tid = threadIdx.x;
  const int lane = tid & 63, wid = tid >> 6;
  const int wr = wid >> 1, wc = wid & 1;
  const int l16 = lane & 15, lh = lane >> 4;

  if (tid < 128) {
    int r = m0 + tid;
    gids[tid] = (r < N_NODES) ? gid[r] : -1;
  }

  f32x4 acc[4][4];
#pragma unroll
  for (int i = 0; i < 4; i++)
#pragma unroll
    for (int j = 0; j < 4; j++) acc[i][j] = (f32x4){0.f, 0.f, 0.f, 0.f};

  const short* ap0 = h2 + (size_t)(m0 + (tid >> 2)) * HID + (tid & 3) * 8;
  const short* ap1 = ap0 + (size_t)64 * HID;
  const short* bp0 = w3t + (size_t)(tid >> 2) * HID + (tid & 3) * 8;
  const short* bp1 = bp0 + (size_t)64 * HID;

  for (int kt = 0; kt < HID / 32; ++kt) {
    __syncthreads();
    gload_lds16(ap0 + kt * 32, &As[tid * 8]);
    gload_lds16(ap1 + kt * 32, &As[tid * 8 + 2048]);
    gload_lds16(bp0 + kt * 32, &Bs[tid * 8]);
    gload_lds16(bp1 + kt * 32, &Bs[tid * 8 + 2048]);
    __syncthreads();
    bf16x8 a[4], b[4];
#pragma unroll
    for (int i = 0; i < 4; i++)
      a[i] = *(const bf16x8*)(&As[(wr * 64 + i * 16 + l16) * 32 + lh * 8]);
#pragma unroll
    for (int j = 0; j < 4; j++)
      b[j] = *(const bf16x8*)(&Bs[(wc * 64 + j * 16 + l16) * 32 + lh * 8]);
#pragma unroll
    for (int i = 0; i < 4; i++)
#pragma unroll
      for (int j = 0; j < 4; j++) acc[i][j] = mfma16(a[i], b[j], acc[i][j]);
  }

  // epilogue: l_enc = acc + jump (jump already holds b3+bj) -> Ll (swizzled bf16)
#pragma unroll
  for (int j = 0; j < 4; j++) {
    const int col = wc * 64 + j * 16 + l16;
#pragma unroll
    for (int i = 0; i < 4; i++) {
      const int rowb = wr * 64 + i * 16 + lh * 4;
#pragma unroll
      for (int r = 0; r < 4; r++) {
        const int row = rowb + r;
        float v = acc[i][j][r] + bf2f(jmp[(size_t)(m0 + row) * OUTD + col]);
        unsigned byte = (unsigned)row * 256u +
                        (((unsigned)col * 2u) ^ (((unsigned)(row & 7)) << 4));
        *(short*)((char*)Ll + byte) = f2bf(v);
      }
    }
  }
  __syncthreads();

  int myg[4][4];
#pragma unroll
  for (int i = 0; i < 4; i++)
#pragma unroll
    for (int r = 0; r < 4; r++) myg[i][r] = gids[wr * 64 + i * 16 + lh * 4 + r];

  float pacc = 0.f, nacc = 0.f;
  for (int nc = 0; nc < 4; ++nc) {
    f32x4 a2[4][4];
#pragma unroll
    for (int i = 0; i < 4; i++)
#pragma unroll
      for (int j = 0; j < 4; j++) a2[i][j] = (f32x4){0.f, 0.f, 0.f, 0.f};
#pragma unroll
    for (int ks = 0; ks < 4; ++ks) {
      bf16x8 af[4], bg[4];
#pragma unroll
      for (int i = 0; i < 4; i++) {
        const int row = wr * 64 + i * 16 + l16;
        unsigned byte = (unsigned)row * 256u +
                        (((unsigned)(ks * 64 + lh * 16)) ^ (((unsigned)(row & 7)) << 4));
        af[i] = *(const bf16x8*)((const char*)Ll + byte);
      }
#pragma unroll
      for (int j = 0; j < 4; j++) {
        const int g = nc * 128 + wc * 64 + j * 16 + l16;
        bg[j] = *(const bf16x8*)(genc + (size_t)g * OUTD + ks * 32 + lh * 8);
      }
#pragma unroll
      for (int i = 0; i < 4; i++)
#pragma unroll
        for (int j = 0; j < 4; j++) a2[i][j] = mfma16(af[i], bg[j], a2[i][j]);
    }
#pragma unroll
    for (int j = 0; j < 4; j++) {
      const int g = nc * 128 + wc * 64 + j * 16 + l16;
#pragma unroll
      for (int i = 0; i < 4; i++) {
#pragma unroll
        for (int r = 0; r < 4; r++) {
          float rv = a2[i][j][r];
          int gr = myg[i][r];
          float t = __expf(-fabsf(rv));
          float lg = __logf(1.f + t);
          if (gr == g)
            pacc += LOG2F_ - (fmaxf(-rv, 0.f) + lg);
          else if (gr >= 0)
            nacc += (fmaxf(rv, 0.f) + lg) - LOG2F_;
        }
      }
    }
  }

#pragma unroll
  for (int o = 32; o; o >>= 1) {
    pacc += __shfl_down(pacc, o);
    nacc += __shfl_down(nacc, o);
  }
  if (lane == 0) { sred[wid] = pacc; sred[4 + wid] = nacc; }
  __syncthreads();
  if (tid == 0) {
    partials[2 * mt] = sred[0] + sred[1] + sred[2] + sred[3];
    partials[2 * mt + 1] = sred[4] + sred[5] + sred[6] + sred[7];
  }
}

// ---------------- K4: deterministic final reduction ---------------------------
__global__ void k4(const float* __restrict__ partials, float* __restrict__ out) {
  const int tid = threadIdx.x;
  float p = 0.f, n = 0.f;
  for (int i = tid; i < MT; i += 256) {
    p += partials[2 * i];
    n += partials[2 * i + 1];
  }
#pragma unroll
  for (int o = 32; o; o >>= 1) {
    p += __shfl_down(p, o);
    n += __shfl_down(n, o);
  }
  __shared__ float sp[4], sn[4];
  const int wid = tid >> 6, lane = tid & 63;
  if (lane == 0) { sp[wid] = p; sn[wid] = n; }
  __syncthreads();
  if (tid == 0) {
    float P = sp[0] + sp[1] + sp[2] + sp[3];
    float Nn = sn[0] + sn[1] + sn[2] + sn[3];
    out[0] = Nn / (100000.0f * 511.0f) - P / 100000.0f;
  }
}

extern "C" void kernel_launch(void* const* d_in, const int* in_sizes, int n_in,
                              void* d_out, int out_size, void* d_ws, size_t ws_size,
                              hipStream_t stream) {
  const float* feat = (const float*)d_in[0];
  const float* genc_f = (const float*)d_in[1];
  const int* gid = (const int*)d_in[2];
  const float* W1 = (const float*)d_in[3];
  const float* b1 = (const float*)d_in[4];
  const float* W2 = (const float*)d_in[5];
  const float* b2 = (const float*)d_in[6];
  const float* W3 = (const float*)d_in[7];
  const float* b3 = (const float*)d_in[8];
  const float* Wj = (const float*)d_in[9];
  const float* bj = (const float*)d_in[10];
  float* out = (float*)d_out;

  char* ws = (char*)d_ws;
  float* partials = (float*)ws;                       // 782*2 f32
  short* wcatF = (short*)(ws + 8192);                 // [640][2048] bf16 frag-major
  short* w2tF = wcatF + (size_t)640 * 2048;           // [512][512] frag-major
  short* w3t = w2tF + (size_t)512 * 512;              // [128][512] row-major
  short* gencb = w3t + (size_t)128 * 512;             // [512][128] row-major
  short* h1 = gencb + (size_t)512 * 128;              // [MPAD][512]
  short* h2 = h1 + (size_t)MPAD * 512;                // [MPAD][512]
  short* jmp = h2 + (size_t)MPAD * 512;               // [MPAD][128]

  kprep<<<6656, 256, 0, stream>>>(W1, Wj, W2, W3, genc_f, wcatF, w2tF, w3t, gencb);
  k1<<<MT64, 512, 0, stream>>>(feat, wcatF, b1, b3, bj, h1, jmp);
  k2<<<MT64, 512, 0, stream>>>(h1, w2tF, b2, h2);
  k3<<<MT, 256, 0, stream>>>(h2, w3t, jmp, gencb, gid, partials);
  k4<<<1, 256, 0, stream>>>(partials, out);
}